// Round 1
// baseline (52.372 us; speedup 1.0000x reference)
//
#include <hip/hip_runtime.h>

#define VOCAB 30522
#define SEQ 512
#define HWORDS (VOCAB / 2)   // 15261 packed uint32 words (2 x uint16 counts)

__global__ __launch_bounds__(512) void bow_hist_kernel(const int* __restrict__ ids,
                                                       float* __restrict__ out,
                                                       int B) {
    __shared__ unsigned int hist[HWORDS];
    __shared__ int s_cut;

    const int b   = blockIdx.x;
    const int tid = threadIdx.x;
    if (b >= B) return;

    if (tid == 0) s_cut = SEQ;

    // Zero the packed histogram (61 KB LDS).
    for (int i = tid; i < HWORDS; i += 512) hist[i] = 0u;

    // One token per thread (blockDim == SEQ == 512).
    const int tok = ids[(size_t)b * SEQ + tid];

    __syncthreads();

    // First-pad cutoff: token t is valid iff t < min index of a pad token.
    if (tok == 0) atomicMin(&s_cut, tid);
    __syncthreads();

    // Scatter into LDS. Counts per row <= 512 so uint16 halves never carry.
    if (tid < s_cut) {
        atomicAdd(&hist[tok >> 1], 1u << ((tok & 1) << 4));
    }
    __syncthreads();

    // Stream the full row out, coalesced float2 stores (row base is 8B-aligned:
    // 30522 * 4 = 122088 bytes, divisible by 8).
    float* orow = out + (size_t)b * VOCAB;
    for (int i = tid; i < HWORDS; i += 512) {
        const unsigned int w = hist[i];
        float2 f = make_float2((float)(w & 0xFFFFu), (float)(w >> 16));
        *reinterpret_cast<float2*>(orow + 2 * i) = f;
    }
}

extern "C" void kernel_launch(void* const* d_in, const int* in_sizes, int n_in,
                              void* d_out, int out_size, void* d_ws, size_t ws_size,
                              hipStream_t stream) {
    const int* ids = (const int*)d_in[0];
    float* out     = (float*)d_out;
    const int B    = in_sizes[0] / SEQ;   // 2048

    bow_hist_kernel<<<B, 512, 0, stream>>>(ids, out, B);
}

// Round 2
// 39.141 us; speedup vs baseline: 1.3380x; 1.3380x over previous
//
#include <hip/hip_runtime.h>

#define VOCAB 30522
#define SEQ 512
#define NQ 4                       // vocab quarters per row
#define QENT 7632                  // vocab entries per quarter (last covers 7626)
#define QWORDS (QENT / 2)          // 3816 packed uint32 words (2 x uint16 counts)

__global__ __launch_bounds__(256) void bow_hist_kernel(const int* __restrict__ ids,
                                                       float* __restrict__ out) {
    __shared__ unsigned int hist[QWORDS];   // 15264 B
    __shared__ int s_cut;

    const int blk = blockIdx.x;
    const int b   = blk >> 2;      // row
    const int q   = blk & 3;       // vocab quarter
    const int tid = threadIdx.x;

    if (tid == 0) s_cut = SEQ;

    // Zero the packed quarter-histogram.
    for (int i = tid; i < QWORDS; i += 256) hist[i] = 0u;

    // 512 tokens, 2 per thread.
    const int t0 = ids[(size_t)b * SEQ + tid];
    const int t1 = ids[(size_t)b * SEQ + tid + 256];

    __syncthreads();

    // First-pad cutoff: token t counts iff t < min index of any pad token.
    if (t0 == 0) atomicMin(&s_cut, tid);
    if (t1 == 0) atomicMin(&s_cut, tid + 256);
    __syncthreads();

    const int cut = s_cut;
    const int lo  = q * QENT;

    // Scatter tokens belonging to this quarter. uint16 halves never carry
    // (max count per row is 512 < 65536).
    if (tid < cut) {
        const int r = t0 - lo;
        if ((unsigned)r < (unsigned)QENT)
            atomicAdd(&hist[r >> 1], 1u << ((r & 1) << 4));
    }
    if (tid + 256 < cut) {
        const int r = t1 - lo;
        if ((unsigned)r < (unsigned)QENT)
            atomicAdd(&hist[r >> 1], 1u << ((r & 1) << 4));
    }
    __syncthreads();

    // Stream the quarter out, coalesced float2 stores (region base is always
    // 8B-aligned: b*122088 + q*30528 bytes, both multiples of 8).
    const int nw = (q == NQ - 1) ? (VOCAB - (NQ - 1) * QENT) / 2 : QWORDS; // 3813 or 3816
    float* obase = out + (size_t)b * VOCAB + lo;
    for (int i = tid; i < nw; i += 256) {
        const unsigned int w = hist[i];
        float2 f = make_float2((float)(w & 0xFFFFu), (float)(w >> 16));
        *reinterpret_cast<float2*>(obase + 2 * i) = f;
    }
}

extern "C" void kernel_launch(void* const* d_in, const int* in_sizes, int n_in,
                              void* d_out, int out_size, void* d_ws, size_t ws_size,
                              hipStream_t stream) {
    const int* ids = (const int*)d_in[0];
    float* out     = (float*)d_out;
    const int B    = in_sizes[0] / SEQ;   // 2048

    bow_hist_kernel<<<B * NQ, 256, 0, stream>>>(ids, out);
}

// Round 3
// 39.004 us; speedup vs baseline: 1.3427x; 1.0035x over previous
//
#include <hip/hip_runtime.h>

#define VOCAB 30522
#define SEQ 512
#define NQ 4                       // vocab quarters per row
#define QENT 7632                  // vocab entries per quarter (last covers 7626)
#define QWORDS (QENT / 2)          // 3816 packed uint32 words (2 x uint16 counts)

__global__ __launch_bounds__(256) void bow_row_kernel(const int* __restrict__ ids,
                                                      float* __restrict__ out) {
    __shared__ unsigned int hist[QWORDS];   // 15264 B -> 8 blocks/CU (thread-limited)
    __shared__ int s_cut;

    const int b   = blockIdx.x;    // one block per row
    const int tid = threadIdx.x;

    if (tid == 0) s_cut = SEQ;

    // Issue the row's token loads (512 tokens, 2/thread), then zero the
    // quarter-0 histogram under the load latency shadow.
    const int t0 = ids[(size_t)b * SEQ + tid];
    const int t1 = ids[(size_t)b * SEQ + tid + 256];

    for (int i = tid; i < QWORDS; i += 256) hist[i] = 0u;
    __syncthreads();

    // First-pad cutoff: token t counts iff t < min index of any pad token.
    if (t0 == 0) atomicMin(&s_cut, tid);
    if (t1 == 0) atomicMin(&s_cut, tid + 256);
    __syncthreads();

    const int  cut = s_cut;
    const bool v0  = tid < cut;
    const bool v1  = tid + 256 < cut;

    float* orow = out + (size_t)b * VOCAB;

    for (int q = 0; q < NQ; ++q) {
        const int lo = q * QENT;

        // Scatter this quarter's tokens. uint16 halves never carry (<=512/row).
        if (v0) {
            const int r = t0 - lo;
            if ((unsigned)r < (unsigned)QENT)
                atomicAdd(&hist[r >> 1], 1u << ((r & 1) << 4));
        }
        if (v1) {
            const int r = t1 - lo;
            if ((unsigned)r < (unsigned)QENT)
                atomicAdd(&hist[r >> 1], 1u << ((r & 1) << 4));
        }
        __syncthreads();

        // Stream the quarter out, coalesced float2 stores (base always 8B-aligned).
        const int nw = (q == NQ - 1) ? (VOCAB - (NQ - 1) * QENT) / 2 : QWORDS; // 3813 last
        float* obase = orow + lo;
        for (int i = tid; i < nw; i += 256) {
            const unsigned int w = hist[i];
            float2 f = make_float2((float)(w & 0xFFFFu), (float)(w >> 16));
            *reinterpret_cast<float2*>(obase + 2 * i) = f;
        }

        if (q < NQ - 1) {
            __syncthreads();   // hist reads done before re-zero
            for (int i = tid; i < QWORDS; i += 256) hist[i] = 0u;
            __syncthreads();   // zero done before next scatter
        }
    }
}

extern "C" void kernel_launch(void* const* d_in, const int* in_sizes, int n_in,
                              void* d_out, int out_size, void* d_ws, size_t ws_size,
                              hipStream_t stream) {
    const int* ids = (const int*)d_in[0];
    float* out     = (float*)d_out;
    const int B    = in_sizes[0] / SEQ;   // 2048

    bow_row_kernel<<<B, 256, 0, stream>>>(ids, out);
}